// Round 1
// baseline (857.928 us; speedup 1.0000x reference)
//
#include <hip/hip_runtime.h>
#include <hip/hip_bf16.h>

typedef unsigned short b16;
typedef __attribute__((ext_vector_type(8))) unsigned short us8;
typedef __attribute__((ext_vector_type(8))) short short8;   // MFMA A/B frag (8 bf16)
typedef __attribute__((ext_vector_type(4))) float float4v;  // MFMA C/D frag

#define NN 100000
#define NE 600000

__device__ __forceinline__ float bf2f(b16 u) {
    return __uint_as_float(((unsigned)u) << 16);
}
__device__ __forceinline__ b16 f2bf(float f) {
    unsigned x = __float_as_uint(f);
    return (b16)((x + 0x7fffu + ((x >> 16) & 1u)) >> 16);
}

// ---------- dtype detection: flags[0]=1 if float tensors fp32, flags[1]=1 if idx int64
__global__ void k_detect(const void* __restrict__ y, const void* __restrict__ ei,
                         int* __restrict__ flags) {
    if (threadIdx.x == 0 && blockIdx.x == 0) {
        const b16* p = (const b16*)y;
        int f32 = 0;
        for (int i = 0; i < 128; ++i) {
            float v = bf2f(p[i]);
            if (!(fabsf(v) < 1e4f)) { f32 = 1; break; }
        }
        flags[0] = f32;
        const long long* q = (const long long*)ei;
        int i64 = 1;
        for (int i = 0; i < 4; ++i) {
            long long v = q[i];
            if (v < 0 || v >= NN) i64 = 0;
        }
        flags[1] = i64;
    }
}

__global__ void k_cvt(const void* __restrict__ in, float* __restrict__ out, int n,
                      const int* __restrict__ flags) {
    int i = blockIdx.x * blockDim.x + threadIdx.x;
    if (i >= n) return;
    out[i] = flags[0] ? ((const float*)in)[i] : bf2f(((const b16*)in)[i]);
}

// ---------- edge_index normalize ----------
__global__ void k_idx(const void* __restrict__ ei, int* __restrict__ src32,
                      int* __restrict__ dst32, const int* __restrict__ flags) {
    int e = blockIdx.x * blockDim.x + threadIdx.x;
    if (e >= NE) return;
    int s, d;
    if (flags[1]) {
        const long long* p = (const long long*)ei;
        s = (int)p[e];
        d = (int)p[NE + e];
    } else {
        const int* p = (const int*)ei;
        s = p[e];
        d = p[NE + e];
    }
    src32[e] = ((unsigned)s < NN) ? s : 0;
    dst32[e] = ((unsigned)d < NN) ? d : 0;
}

// ---------- degree (weighted) + CSR count ----------
__global__ void k_degcnt(const int* __restrict__ dst, const void* __restrict__ ea,
                         float* __restrict__ deg, int* __restrict__ cnt,
                         const int* __restrict__ flags) {
    int e = blockIdx.x * blockDim.x + threadIdx.x;
    if (e >= NE) return;
    float w = flags[0] ? ((const float*)ea)[e] : bf2f(((const b16*)ea)[e]);
    int d = dst[e];
    unsafeAtomicAdd(&deg[d], w);
    atomicAdd(&cnt[d], 1);
}

__global__ void k_dis(float* deg) {
    int n = blockIdx.x * blockDim.x + threadIdx.x;
    if (n < NN) {
        float d = deg[n];
        deg[n] = (d > 0.f) ? rsqrtf(fmaxf(d, 1e-12f)) : 0.f;
    }
}

// ---------- 3-phase exclusive scan of cnt[NN] -> rowptr[NN+1] ----------
#define SCAN_B 1024
#define SCAN_NB ((NN + SCAN_B - 1) / SCAN_B)

__global__ __launch_bounds__(SCAN_B) void k_scan1(const int* __restrict__ cnt,
                                                  int* __restrict__ inc,
                                                  int* __restrict__ bsum) {
    __shared__ int s[SCAN_B];
    int i = blockIdx.x * SCAN_B + threadIdx.x;
    s[threadIdx.x] = (i < NN) ? cnt[i] : 0;
    __syncthreads();
    for (int off = 1; off < SCAN_B; off <<= 1) {
        int t = (threadIdx.x >= off) ? s[threadIdx.x - off] : 0;
        __syncthreads();
        s[threadIdx.x] += t;
        __syncthreads();
    }
    if (i < NN) inc[i] = s[threadIdx.x];
    if (threadIdx.x == SCAN_B - 1) bsum[blockIdx.x] = s[SCAN_B - 1];
}

// wave-parallel exclusive scan over SCAN_NB (=98) block sums; 1 wave of 64 lanes
__global__ void k_scan2(int* bsum) {
    int lane = threadIdx.x & 63;
    int a0 = (lane < SCAN_NB) ? bsum[lane] : 0;
    int a1 = (lane + 64 < SCAN_NB) ? bsum[lane + 64] : 0;
#pragma unroll
    for (int off = 1; off < 64; off <<= 1) {
        int t = __shfl_up(a0, off);
        if (lane >= off) a0 += t;
    }
    int tot0 = __shfl(a0, 63);
#pragma unroll
    for (int off = 1; off < 64; off <<= 1) {
        int t = __shfl_up(a1, off);
        if (lane >= off) a1 += t;
    }
    int e0 = __shfl_up(a0, 1);
    if (lane == 0) e0 = 0;
    int e1 = __shfl_up(a1, 1) + tot0;
    if (lane == 0) e1 = tot0;
    if (lane < SCAN_NB) bsum[lane] = e0;
    if (lane + 64 < SCAN_NB) bsum[lane + 64] = e1;
}

__global__ void k_scan3(const int* __restrict__ inc, const int* __restrict__ bsum,
                        int* __restrict__ rowptr) {
    int i = blockIdx.x * blockDim.x + threadIdx.x;
    if (i == 0) rowptr[0] = 0;
    if (i < NN) rowptr[i + 1] = inc[i] + bsum[i / SCAN_B];
}

// ---------- fill CSR ----------
__global__ void k_fill(const int* __restrict__ src, const int* __restrict__ dst,
                       const void* __restrict__ ea, const float* __restrict__ dis,
                       const int* __restrict__ rowptr, int* __restrict__ fill,
                       int* __restrict__ csrc, float* __restrict__ cw,
                       const int* __restrict__ flags) {
    int e = blockIdx.x * blockDim.x + threadIdx.x;
    if (e >= NE) return;
    float a = flags[0] ? ((const float*)ea)[e] : bf2f(((const b16*)ea)[e]);
    int d = dst[e];
    int s = src[e];
    int pos = rowptr[d] + atomicAdd(&fill[d], 1);
    csrc[pos] = s;
    cw[pos] = dis[s] * a * dis[d];
}

// ---------- pack W (fp32/bf16 [512][NC]) into B-fragment order ----------
__global__ void k_pack(const void* __restrict__ W, b16* __restrict__ Wp, int NC,
                       const int* __restrict__ flags) {
    int f = blockIdx.x * blockDim.x + threadIdx.x;
    int total = 512 * NC / 8;
    if (f >= total) return;
    int lane = f & 63;
    int rest = f >> 6;
    int CT = NC >> 4;
    int ct = rest % CT, ks = rest / CT;
    int k0 = 32 * ks + (lane >> 4) * 8;
    int col = 16 * ct + (lane & 15);
    us8 v;
#pragma unroll
    for (int j = 0; j < 8; ++j) {
        float x = flags[0] ? ((const float*)W)[(size_t)(k0 + j) * NC + col]
                           : bf2f(((const b16*)W)[(size_t)(k0 + j) * NC + col]);
        v[j] = f2bf(x);
    }
    *(us8*)&Wp[(size_t)f * 8] = v;
}

// ---------- initial cast y -> XC cols [0,128) (bf16, row stride 512) ----------
__global__ void k_cast(const void* __restrict__ y, b16* __restrict__ XC,
                       const int* __restrict__ flags) {
    int i = blockIdx.x * blockDim.x + threadIdx.x;
    if (i >= NN * 32) return;
    int row = i >> 5, cg = i & 31;
    float4 v;
    if (flags[0]) {
        v = ((const float4*)y)[i];
    } else {
        ushort4 u = ((const ushort4*)y)[i];
        v = make_float4(bf2f(u.x), bf2f(u.y), bf2f(u.z), bf2f(u.w));
    }
    ushort4 o;
    o.x = f2bf(v.x); o.y = f2bf(v.y); o.z = f2bf(v.z); o.w = f2bf(v.w);
    *(ushort4*)&XC[(size_t)row * 512 + 4 * cg] = o;
}

// ---------- SpMM gather: cols [ci,ci+128) -> [co,co+128) ----------
// wave = 1 node; quarter-wave (16 lanes x us8) = 256B row segment per edge.
__global__ __launch_bounds__(256) void k_spmm(b16* __restrict__ XC, int ci, int co,
                                              const int* __restrict__ rowptr,
                                              const int* __restrict__ csrc,
                                              const float* __restrict__ cw) {
    int gid = blockIdx.x * blockDim.x + threadIdx.x;
    int node = gid >> 6;
    if (node >= NN) return;
    int lane = gid & 63;
    int grp = lane >> 4;  // edge slot 0..3
    int l15 = lane & 15;  // 16B chunk within 256B segment
    int beg = rowptr[node], end = rowptr[node + 1];

    float a0[8], a1[8];
#pragma unroll
    for (int j = 0; j < 8; ++j) {
        a0[j] = 0.f;
        a1[j] = 0.f;
    }
    for (int i = beg; i < end; i += 16) {
        int e0 = i + grp, e1 = i + 4 + grp, e2 = i + 8 + grp, e3 = i + 12 + grp;
        float w0 = (e0 < end) ? cw[e0] : 0.f;
        float w1 = (e1 < end) ? cw[e1] : 0.f;
        float w2 = (e2 < end) ? cw[e2] : 0.f;
        float w3 = (e3 < end) ? cw[e3] : 0.f;
        int lim = end - 1;
        int s0 = csrc[e0 < lim ? e0 : lim];
        int s1 = csrc[e1 < lim ? e1 : lim];
        int s2 = csrc[e2 < lim ? e2 : lim];
        int s3 = csrc[e3 < lim ? e3 : lim];
        us8 u0 = *(const us8*)&XC[(size_t)s0 * 512 + ci + 8 * l15];
        us8 u1 = *(const us8*)&XC[(size_t)s1 * 512 + ci + 8 * l15];
        us8 u2 = *(const us8*)&XC[(size_t)s2 * 512 + ci + 8 * l15];
        us8 u3 = *(const us8*)&XC[(size_t)s3 * 512 + ci + 8 * l15];
#pragma unroll
        for (int j = 0; j < 8; ++j) {
            a0[j] = fmaf(w0, bf2f(u0[j]), a0[j]);
            a1[j] = fmaf(w1, bf2f(u1[j]), a1[j]);
            a0[j] = fmaf(w2, bf2f(u2[j]), a0[j]);
            a1[j] = fmaf(w3, bf2f(u3[j]), a1[j]);
        }
    }
#pragma unroll
    for (int j = 0; j < 8; ++j) a0[j] += a1[j];
#pragma unroll
    for (int j = 0; j < 8; ++j) a0[j] += __shfl_xor(a0[j], 16);
#pragma unroll
    for (int j = 0; j < 8; ++j) a0[j] += __shfl_xor(a0[j], 32);
    if (grp == 0) {
        us8 o;
#pragma unroll
        for (int j = 0; j < 8; ++j) o[j] = f2bf(a0[j]);
        *(us8*)&XC[(size_t)node * 512 + co + 8 * l15] = o;
    }
}

// ---------- MFMA GEMM + fused BN-stat epilogue ----------
// OUT[NN x NC](bf16) = XC[NN x 512](bf16) @ Wp (+bias); col sums/sumsq -> gsum/gsq.
// v2: 16 rows/wave (was 32) -> 6250 waves, grid 1563 blocks, ~5 waves/SIMD
// resident (was 3). B loaded per-ks straight from L2-hot packed Wp (128 KB);
// A keeps depth-1 register prefetch. No LDS, no barriers in main loop.
template <int NC>
__global__ __launch_bounds__(256, 4) void k_mgemm(const b16* __restrict__ XC,
                                                  const b16* __restrict__ Wp,
                                                  const float* __restrict__ bias,
                                                  b16* __restrict__ OUT,
                                                  float* __restrict__ gsum,
                                                  float* __restrict__ gsq) {
    constexpr int CT = NC / 16;
    __shared__ float csum[NC], csq[NC];
    const int tid = threadIdx.x;
    const int wave = tid >> 6;
    const int lane = tid & 63;
    const int quad = lane >> 4;
    const int l15 = lane & 15;
    const int rbase = blockIdx.x * 64 + wave * 16;

    for (int i = tid; i < NC; i += 256) {
        csum[i] = 0.f;
        csq[i] = 0.f;
    }

    float4v acc[CT];
#pragma unroll
    for (int ct = 0; ct < CT; ++ct) acc[ct] = (float4v)(0.f);

    int r = rbase + l15;
    if (r >= NN) r = NN - 1;  // clamp; dead rows excluded from store/stats
    const b16* gA = XC + (size_t)r * 512 + quad * 8;
    const b16* gB = Wp + lane * 8;

    short8 af = *(const short8*)gA;
    for (int ks = 0; ks < 16; ++ks) {
        short8 bf[CT];
        const b16* gBk = gB + (size_t)ks * CT * 512;
#pragma unroll
        for (int ct = 0; ct < CT; ++ct) bf[ct] = *(const short8*)(gBk + ct * 512);
        short8 afn;
        if (ks < 15) afn = *(const short8*)(gA + 32 * (ks + 1));
#pragma unroll
        for (int ct = 0; ct < CT; ++ct)
            acc[ct] = __builtin_amdgcn_mfma_f32_16x16x32_bf16(af, bf[ct], acc[ct],
                                                              0, 0, 0);
        if (ks < 15) af = afn;
    }

    // epilogue: bf16 store + BN stats (C/D: col=lane&15, row=quad*4+reg)
#pragma unroll
    for (int ct = 0; ct < CT; ++ct) {
        int col = 16 * ct + l15;
        float bv = bias ? bias[col] : 0.f;
        float s = 0.f, sq = 0.f;
#pragma unroll
        for (int rr = 0; rr < 4; ++rr) {
            int row = rbase + quad * 4 + rr;
            if (row < NN) {
                float v = acc[ct][rr] + bv;
                OUT[(size_t)row * NC + col] = f2bf(v);
                s += v;
                sq += v * v;
            }
        }
        s += __shfl_xor(s, 16);
        s += __shfl_xor(s, 32);
        sq += __shfl_xor(sq, 16);
        sq += __shfl_xor(sq, 32);
        if (quad == 0) {
            atomicAdd(&csum[col], s);
            atomicAdd(&csq[col], sq);
        }
    }
    __syncthreads();
    for (int i = tid; i < NC; i += 256) {
        unsafeAtomicAdd(&gsum[i], csum[i]);
        unsafeAtomicAdd(&gsq[i], csq[i]);
    }
}

// ---------- BatchNorm params ----------
__global__ void k_bnparam(const float* gsum, const float* gsq, const float* g,
                          const float* be, float* scale, float* shift, int ncols) {
    int c = threadIdx.x;
    if (c < ncols) {
        float m = gsum[c] * (1.f / NN);
        float v = gsq[c] * (1.f / NN) - m * m;
        v = fmaxf(v, 0.f);
        float s = rsqrtf(v + 1e-5f) * g[c];
        scale[c] = s;
        shift[c] = be[c] - m * s;
    }
}

// layers 1,2: write bf16 into XC cols [0,128)
__global__ void k_bnapply_mid(const b16* __restrict__ OUT,
                              const float* __restrict__ scale,
                              const float* __restrict__ shift, b16* __restrict__ XC) {
    int i = blockIdx.x * blockDim.x + threadIdx.x;
    if (i >= NN * 64) return;
    int row = i >> 6, c = (i & 63) * 2;
    ushort2 u = *(const ushort2*)&OUT[(size_t)row * 128 + c];
    float a = fmaf(bf2f(u.x), scale[c], shift[c]);
    float b = fmaf(bf2f(u.y), scale[c + 1], shift[c + 1]);
    a = a > 0.f ? a : 0.01f * a;
    b = b > 0.f ? b : 0.01f * b;
    ushort2 o;
    o.x = f2bf(a);
    o.y = f2bf(b);
    *(ushort2*)&XC[(size_t)row * 512 + c] = o;
}

// layer 3: write d_out (fp32 or bf16 per flag), NC=64
__global__ void k_bnapply_last(const b16* __restrict__ OUT,
                               const float* __restrict__ scale,
                               const float* __restrict__ shift, void* __restrict__ dout,
                               const int* __restrict__ flags) {
    int i = blockIdx.x * blockDim.x + threadIdx.x;
    if (i >= NN * 64) return;
    int c = i & 63;
    float v = fmaf(bf2f(OUT[i]), scale[c], shift[c]);
    v = v > 0.f ? v : 0.01f * v;
    if (flags[0])
        ((float*)dout)[i] = v;
    else
        ((b16*)dout)[i] = f2bf(v);
}

// ---------- driver ----------
#define PB_B1 0
#define PB_B2 128
#define PB_G1 256
#define PB_BE1 384
#define PB_G2 512
#define PB_BE2 640
#define PB_G3 768
#define PB_BE3 832
#define PB_SZ 896

extern "C" void kernel_launch(void* const* d_in, const int* in_sizes, int n_in,
                              void* d_out, int out_size, void* d_ws, size_t ws_size,
                              hipStream_t stream) {
    const void* y   = d_in[0];
    const void* ei  = d_in[1];
    const void* ea  = d_in[2];
    const void* W1  = d_in[3];
    const void* b1  = d_in[4];
    const void* g1  = d_in[5];
    const void* be1 = d_in[6];
    const void* W2  = d_in[7];
    const void* b2  = d_in[8];
    const void* g2  = d_in[9];
    const void* be2 = d_in[10];
    const void* W3  = d_in[11];
    const void* g3  = d_in[12];
    const void* be3 = d_in[13];

    char* w = (char*)d_ws;
    size_t used = 0;
    auto carve = [&](size_t bytes) -> char* {
        char* p = w + used;
        used += (bytes + 255) & ~(size_t)255;
        return p;
    };

    int* flags   = (int*)carve(16);
    int* src32   = (int*)carve((size_t)NE * 4);
    int* dst32   = (int*)carve((size_t)NE * 4);
    float* deg   = (float*)carve((size_t)NN * 4);
    int* cnt     = (int*)carve((size_t)NN * 4);
    int* rowptr  = (int*)carve((size_t)(NN + 1) * 4);
    int* cscan   = (int*)carve((size_t)NN * 4);
    int* bsum    = (int*)carve((size_t)SCAN_NB * 4);
    int* csrc    = (int*)carve((size_t)NE * 4);
    float* cw    = (float*)carve((size_t)NE * 4);
    float* PB    = (float*)carve(PB_SZ * 4);
    b16* Wp1     = (b16*)carve((size_t)512 * 128 * 2);
    b16* Wp2     = (b16*)carve((size_t)512 * 128 * 2);
    b16* Wp3     = (b16*)carve((size_t)512 * 64 * 2);
    b16* OUT     = (b16*)carve((size_t)NN * 128 * 2);
    float* gsum  = (float*)carve(128 * 4);
    float* gsq   = (float*)carve(128 * 4);
    float* scale = (float*)carve(128 * 4);
    float* shift = (float*)carve(128 * 4);
    b16* XC      = (b16*)carve((size_t)NN * 512 * 2);

    // ----- detection + param normalize + weight pack -----
    k_detect<<<1, 64, 0, stream>>>(y, ei, flags);
    auto cvt = [&](const void* in, float* out, int n) {
        k_cvt<<<(n + 127) / 128, 128, 0, stream>>>(in, out, n, flags);
    };
    cvt(b1, PB + PB_B1, 128);
    cvt(b2, PB + PB_B2, 128);
    cvt(g1, PB + PB_G1, 128);
    cvt(be1, PB + PB_BE1, 128);
    cvt(g2, PB + PB_G2, 128);
    cvt(be2, PB + PB_BE2, 128);
    cvt(g3, PB + PB_G3, 64);
    cvt(be3, PB + PB_BE3, 64);
    k_pack<<<(512 * 128 / 8 + 255) / 256, 256, 0, stream>>>(W1, Wp1, 128, flags);
    k_pack<<<(512 * 128 / 8 + 255) / 256, 256, 0, stream>>>(W2, Wp2, 128, flags);
    k_pack<<<(512 * 64 / 8 + 255) / 256, 256, 0, stream>>>(W3, Wp3, 64, flags);

    // ----- graph prep -----
    k_idx<<<(NE + 255) / 256, 256, 0, stream>>>(ei, src32, dst32, flags);
    hipMemsetAsync(deg, 0, (size_t)NN * 4, stream);
    hipMemsetAsync(cnt, 0, (size_t)NN * 4, stream);
    k_degcnt<<<(NE + 255) / 256, 256, 0, stream>>>(dst32, ea, deg, cnt, flags);
    k_dis<<<(NN + 255) / 256, 256, 0, stream>>>(deg);
    k_scan1<<<SCAN_NB, SCAN_B, 0, stream>>>(cnt, cscan, bsum);
    k_scan2<<<1, 64, 0, stream>>>(bsum);
    k_scan3<<<(NN + 255) / 256, 256, 0, stream>>>(cscan, bsum, rowptr);
    hipMemsetAsync(cnt, 0, (size_t)NN * 4, stream);
    k_fill<<<(NE + 255) / 256, 256, 0, stream>>>(src32, dst32, ea, deg, rowptr, cnt,
                                                 csrc, cw, flags);

    // ----- layers -----
    k_cast<<<(NN * 32 + 255) / 256, 256, 0, stream>>>(y, XC, flags);

    auto spmm = [&](int ci, int co) {
        k_spmm<<<(NN * 64 + 255) / 256, 256, 0, stream>>>(XC, ci, co, rowptr, csrc, cw);
    };
    const int gemm_grid = (NN + 63) / 64;

    auto layer = [&](const b16* Wp, const float* bias, const float* g, const float* be,
                     int NC, bool last) {
        spmm(0, 128);
        spmm(128, 256);
        spmm(256, 384);
        hipMemsetAsync(gsum, 0, NC * 4, stream);
        hipMemsetAsync(gsq, 0, NC * 4, stream);
        if (NC == 128)
            k_mgemm<128><<<gemm_grid, 256, 0, stream>>>(XC, Wp, bias, OUT, gsum, gsq);
        else
            k_mgemm<64><<<gemm_grid, 256, 0, stream>>>(XC, Wp, bias, OUT, gsum, gsq);
        k_bnparam<<<1, NC, 0, stream>>>(gsum, gsq, g, be, scale, shift, NC);
        if (last)
            k_bnapply_last<<<(NN * 64 + 255) / 256, 256, 0, stream>>>(OUT, scale, shift,
                                                                      d_out, flags);
        else
            k_bnapply_mid<<<(NN * 64 + 255) / 256, 256, 0, stream>>>(OUT, scale, shift,
                                                                     XC);
    };

    layer(Wp1, PB + PB_B1, PB + PB_G1, PB + PB_BE1, 128, false);
    layer(Wp2, PB + PB_B2, PB + PB_G2, PB + PB_BE2, 128, false);
    layer(Wp3, nullptr, PB + PB_G3, PB + PB_BE3, 64, true);
}

// Round 2
// 834.610 us; speedup vs baseline: 1.0279x; 1.0279x over previous
//
#include <hip/hip_runtime.h>
#include <hip/hip_bf16.h>

typedef unsigned short b16;
typedef __attribute__((ext_vector_type(8))) unsigned short us8;
typedef __attribute__((ext_vector_type(8))) short short8;   // MFMA A/B frag (8 bf16)
typedef __attribute__((ext_vector_type(4))) float float4v;  // MFMA C/D frag

#define NN 100000
#define NE 600000

__device__ __forceinline__ float bf2f(b16 u) {
    return __uint_as_float(((unsigned)u) << 16);
}
__device__ __forceinline__ b16 f2bf(float f) {
    unsigned x = __float_as_uint(f);
    return (b16)((x + 0x7fffu + ((x >> 16) & 1u)) >> 16);
}

// ---------- dtype detection: flags[0]=1 if float tensors fp32, flags[1]=1 if idx int64
__global__ void k_detect(const void* __restrict__ y, const void* __restrict__ ei,
                         int* __restrict__ flags) {
    if (threadIdx.x == 0 && blockIdx.x == 0) {
        const b16* p = (const b16*)y;
        int f32 = 0;
        for (int i = 0; i < 128; ++i) {
            float v = bf2f(p[i]);
            if (!(fabsf(v) < 1e4f)) { f32 = 1; break; }
        }
        flags[0] = f32;
        const long long* q = (const long long*)ei;
        int i64 = 1;
        for (int i = 0; i < 4; ++i) {
            long long v = q[i];
            if (v < 0 || v >= NN) i64 = 0;
        }
        flags[1] = i64;
    }
}

__global__ void k_cvt(const void* __restrict__ in, float* __restrict__ out, int n,
                      const int* __restrict__ flags) {
    int i = blockIdx.x * blockDim.x + threadIdx.x;
    if (i >= n) return;
    out[i] = flags[0] ? ((const float*)in)[i] : bf2f(((const b16*)in)[i]);
}

// ---------- edge_index normalize ----------
__global__ void k_idx(const void* __restrict__ ei, int* __restrict__ src32,
                      int* __restrict__ dst32, const int* __restrict__ flags) {
    int e = blockIdx.x * blockDim.x + threadIdx.x;
    if (e >= NE) return;
    int s, d;
    if (flags[1]) {
        const long long* p = (const long long*)ei;
        s = (int)p[e];
        d = (int)p[NE + e];
    } else {
        const int* p = (const int*)ei;
        s = p[e];
        d = p[NE + e];
    }
    src32[e] = ((unsigned)s < NN) ? s : 0;
    dst32[e] = ((unsigned)d < NN) ? d : 0;
}

// ---------- degree (weighted) + CSR count ----------
__global__ void k_degcnt(const int* __restrict__ dst, const void* __restrict__ ea,
                         float* __restrict__ deg, int* __restrict__ cnt,
                         const int* __restrict__ flags) {
    int e = blockIdx.x * blockDim.x + threadIdx.x;
    if (e >= NE) return;
    float w = flags[0] ? ((const float*)ea)[e] : bf2f(((const b16*)ea)[e]);
    int d = dst[e];
    unsafeAtomicAdd(&deg[d], w);
    atomicAdd(&cnt[d], 1);
}

__global__ void k_dis(float* deg) {
    int n = blockIdx.x * blockDim.x + threadIdx.x;
    if (n < NN) {
        float d = deg[n];
        deg[n] = (d > 0.f) ? rsqrtf(fmaxf(d, 1e-12f)) : 0.f;
    }
}

// ---------- 3-phase exclusive scan of cnt[NN] -> rowptr[NN+1] ----------
#define SCAN_B 1024
#define SCAN_NB ((NN + SCAN_B - 1) / SCAN_B)

__global__ __launch_bounds__(SCAN_B) void k_scan1(const int* __restrict__ cnt,
                                                  int* __restrict__ inc,
                                                  int* __restrict__ bsum) {
    __shared__ int s[SCAN_B];
    int i = blockIdx.x * SCAN_B + threadIdx.x;
    s[threadIdx.x] = (i < NN) ? cnt[i] : 0;
    __syncthreads();
    for (int off = 1; off < SCAN_B; off <<= 1) {
        int t = (threadIdx.x >= off) ? s[threadIdx.x - off] : 0;
        __syncthreads();
        s[threadIdx.x] += t;
        __syncthreads();
    }
    if (i < NN) inc[i] = s[threadIdx.x];
    if (threadIdx.x == SCAN_B - 1) bsum[blockIdx.x] = s[SCAN_B - 1];
}

// wave-parallel exclusive scan over SCAN_NB (=98) block sums; 1 wave of 64 lanes
__global__ void k_scan2(int* bsum) {
    int lane = threadIdx.x & 63;
    int a0 = (lane < SCAN_NB) ? bsum[lane] : 0;
    int a1 = (lane + 64 < SCAN_NB) ? bsum[lane + 64] : 0;
#pragma unroll
    for (int off = 1; off < 64; off <<= 1) {
        int t = __shfl_up(a0, off);
        if (lane >= off) a0 += t;
    }
    int tot0 = __shfl(a0, 63);
#pragma unroll
    for (int off = 1; off < 64; off <<= 1) {
        int t = __shfl_up(a1, off);
        if (lane >= off) a1 += t;
    }
    int e0 = __shfl_up(a0, 1);
    if (lane == 0) e0 = 0;
    int e1 = __shfl_up(a1, 1) + tot0;
    if (lane == 0) e1 = tot0;
    if (lane < SCAN_NB) bsum[lane] = e0;
    if (lane + 64 < SCAN_NB) bsum[lane + 64] = e1;
}

__global__ void k_scan3(const int* __restrict__ inc, const int* __restrict__ bsum,
                        int* __restrict__ rowptr) {
    int i = blockIdx.x * blockDim.x + threadIdx.x;
    if (i == 0) rowptr[0] = 0;
    if (i < NN) rowptr[i + 1] = inc[i] + bsum[i / SCAN_B];
}

// ---------- fill CSR ----------
__global__ void k_fill(const int* __restrict__ src, const int* __restrict__ dst,
                       const void* __restrict__ ea, const float* __restrict__ dis,
                       const int* __restrict__ rowptr, int* __restrict__ fill,
                       int* __restrict__ csrc, float* __restrict__ cw,
                       const int* __restrict__ flags) {
    int e = blockIdx.x * blockDim.x + threadIdx.x;
    if (e >= NE) return;
    float a = flags[0] ? ((const float*)ea)[e] : bf2f(((const b16*)ea)[e]);
    int d = dst[e];
    int s = src[e];
    int pos = rowptr[d] + atomicAdd(&fill[d], 1);
    csrc[pos] = s;
    cw[pos] = dis[s] * a * dis[d];
}

// ---------- pack W (fp32/bf16 [512][NC]) into B-fragment order ----------
__global__ void k_pack(const void* __restrict__ W, b16* __restrict__ Wp, int NC,
                       const int* __restrict__ flags) {
    int f = blockIdx.x * blockDim.x + threadIdx.x;
    int total = 512 * NC / 8;
    if (f >= total) return;
    int lane = f & 63;
    int rest = f >> 6;
    int CT = NC >> 4;
    int ct = rest % CT, ks = rest / CT;
    int k0 = 32 * ks + (lane >> 4) * 8;
    int col = 16 * ct + (lane & 15);
    us8 v;
#pragma unroll
    for (int j = 0; j < 8; ++j) {
        float x = flags[0] ? ((const float*)W)[(size_t)(k0 + j) * NC + col]
                           : bf2f(((const b16*)W)[(size_t)(k0 + j) * NC + col]);
        v[j] = f2bf(x);
    }
    *(us8*)&Wp[(size_t)f * 8] = v;
}

// ---------- initial cast y -> XC cols [0,128) (bf16, row stride 512) ----------
__global__ void k_cast(const void* __restrict__ y, b16* __restrict__ XC,
                       const int* __restrict__ flags) {
    int i = blockIdx.x * blockDim.x + threadIdx.x;
    if (i >= NN * 32) return;
    int row = i >> 5, cg = i & 31;
    float4 v;
    if (flags[0]) {
        v = ((const float4*)y)[i];
    } else {
        ushort4 u = ((const ushort4*)y)[i];
        v = make_float4(bf2f(u.x), bf2f(u.y), bf2f(u.z), bf2f(u.w));
    }
    ushort4 o;
    o.x = f2bf(v.x); o.y = f2bf(v.y); o.z = f2bf(v.z); o.w = f2bf(v.w);
    *(ushort4*)&XC[(size_t)row * 512 + 4 * cg] = o;
}

// ---------- SpMM gather: cols [ci,ci+128) -> [co,co+128) ----------
// wave = 1 node; quarter-wave (16 lanes x us8) = 256B row segment per edge.
__global__ __launch_bounds__(256) void k_spmm(b16* __restrict__ XC, int ci, int co,
                                              const int* __restrict__ rowptr,
                                              const int* __restrict__ csrc,
                                              const float* __restrict__ cw) {
    int gid = blockIdx.x * blockDim.x + threadIdx.x;
    int node = gid >> 6;
    if (node >= NN) return;
    int lane = gid & 63;
    int grp = lane >> 4;  // edge slot 0..3
    int l15 = lane & 15;  // 16B chunk within 256B segment
    int beg = rowptr[node], end = rowptr[node + 1];

    float a0[8], a1[8];
#pragma unroll
    for (int j = 0; j < 8; ++j) {
        a0[j] = 0.f;
        a1[j] = 0.f;
    }
    for (int i = beg; i < end; i += 16) {
        int e0 = i + grp, e1 = i + 4 + grp, e2 = i + 8 + grp, e3 = i + 12 + grp;
        float w0 = (e0 < end) ? cw[e0] : 0.f;
        float w1 = (e1 < end) ? cw[e1] : 0.f;
        float w2 = (e2 < end) ? cw[e2] : 0.f;
        float w3 = (e3 < end) ? cw[e3] : 0.f;
        int lim = end - 1;
        int s0 = csrc[e0 < lim ? e0 : lim];
        int s1 = csrc[e1 < lim ? e1 : lim];
        int s2 = csrc[e2 < lim ? e2 : lim];
        int s3 = csrc[e3 < lim ? e3 : lim];
        us8 u0 = *(const us8*)&XC[(size_t)s0 * 512 + ci + 8 * l15];
        us8 u1 = *(const us8*)&XC[(size_t)s1 * 512 + ci + 8 * l15];
        us8 u2 = *(const us8*)&XC[(size_t)s2 * 512 + ci + 8 * l15];
        us8 u3 = *(const us8*)&XC[(size_t)s3 * 512 + ci + 8 * l15];
#pragma unroll
        for (int j = 0; j < 8; ++j) {
            a0[j] = fmaf(w0, bf2f(u0[j]), a0[j]);
            a1[j] = fmaf(w1, bf2f(u1[j]), a1[j]);
            a0[j] = fmaf(w2, bf2f(u2[j]), a0[j]);
            a1[j] = fmaf(w3, bf2f(u3[j]), a1[j]);
        }
    }
#pragma unroll
    for (int j = 0; j < 8; ++j) a0[j] += a1[j];
#pragma unroll
    for (int j = 0; j < 8; ++j) a0[j] += __shfl_xor(a0[j], 16);
#pragma unroll
    for (int j = 0; j < 8; ++j) a0[j] += __shfl_xor(a0[j], 32);
    if (grp == 0) {
        us8 o;
#pragma unroll
        for (int j = 0; j < 8; ++j) o[j] = f2bf(a0[j]);
        *(us8*)&XC[(size_t)node * 512 + co + 8 * l15] = o;
    }
}

// ---------- MFMA GEMM + fused BN-stat epilogue ----------
// OUT[NN x NC](bf16) = XC[NN x 512](bf16) @ Wp (+bias); col sums/sumsq -> gsum/gsq.
// v3: block = 64 rows x NC cols, 4 waves; wave = 32 rows x NC/2 cols.
//   - 6250 waves (grid 1563) -> ~5 waves/SIMD resident (v0 was grid-capped at 3)
//   - per-wave B traffic = Wp/2 -> total B L2 traffic 400 MB (same as v0, half of v1)
//   - depth-1 register prefetch of BOTH A and B restored (v1 dropped B prefetch
//     and its launch_bounds(,4) VGPR cap serialized the loads: VGPR 36, Mfma 5%)
//   - plain __launch_bounds__(256): let compiler keep ~110 VGPR for full ILP
template <int NC>
__global__ __launch_bounds__(256) void k_mgemm(const b16* __restrict__ XC,
                                               const b16* __restrict__ Wp,
                                               const float* __restrict__ bias,
                                               b16* __restrict__ OUT,
                                               float* __restrict__ gsum,
                                               float* __restrict__ gsq) {
    constexpr int CT = NC / 16;   // col tiles total
    constexpr int CTH = CT / 2;   // col tiles per wave
    __shared__ float csum[NC], csq[NC];
    const int tid = threadIdx.x;
    const int wave = tid >> 6;
    const int lane = tid & 63;
    const int quad = lane >> 4;
    const int l15 = lane & 15;
    const int wr = wave >> 1;  // row half 0..1
    const int wc = wave & 1;   // col half 0..1
    const int rbase = blockIdx.x * 64 + wr * 32;

    for (int i = tid; i < NC; i += 256) {
        csum[i] = 0.f;
        csq[i] = 0.f;
    }

    float4v acc[2][CTH];
#pragma unroll
    for (int rt = 0; rt < 2; ++rt)
#pragma unroll
        for (int ct = 0; ct < CTH; ++ct) acc[rt][ct] = (float4v)(0.f);

    const b16* gA[2];
#pragma unroll
    for (int rt = 0; rt < 2; ++rt) {
        int r = rbase + 16 * rt + l15;
        if (r >= NN) r = NN - 1;  // clamp; dead rows excluded from store/stats
        gA[rt] = XC + (size_t)r * 512 + quad * 8;
    }
    // frag (ks, ct) lives at Wp + ((ks*CT + ct)*64 + lane)*8; this wave uses
    // ct in [wc*CTH, wc*CTH+CTH)
    const b16* gB = Wp + ((size_t)(wc * CTH) * 64 + lane) * 8;

    short8 afc[2], bfc[CTH], afn[2], bfn[CTH];
#pragma unroll
    for (int rt = 0; rt < 2; ++rt) afc[rt] = *(const short8*)(gA[rt]);
#pragma unroll
    for (int ct = 0; ct < CTH; ++ct) bfc[ct] = *(const short8*)(gB + ct * 512);

    for (int ks = 0; ks < 16; ++ks) {
        if (ks < 15) {  // prefetch next k-step into regs (issues before MFMA waits)
#pragma unroll
            for (int rt = 0; rt < 2; ++rt)
                afn[rt] = *(const short8*)(gA[rt] + 32 * (ks + 1));
#pragma unroll
            for (int ct = 0; ct < CTH; ++ct)
                bfn[ct] = *(const short8*)(gB + (size_t)((ks + 1) * CT + ct) * 512);
        }
#pragma unroll
        for (int rt = 0; rt < 2; ++rt)
#pragma unroll
            for (int ct = 0; ct < CTH; ++ct)
                acc[rt][ct] = __builtin_amdgcn_mfma_f32_16x16x32_bf16(
                    afc[rt], bfc[ct], acc[rt][ct], 0, 0, 0);
        if (ks < 15) {
#pragma unroll
            for (int rt = 0; rt < 2; ++rt) afc[rt] = afn[rt];
#pragma unroll
            for (int ct = 0; ct < CTH; ++ct) bfc[ct] = bfn[ct];
        }
    }

    // epilogue: bf16 store + BN stats (C/D: col=lane&15, row=quad*4+reg)
#pragma unroll
    for (int rt = 0; rt < 2; ++rt) {
#pragma unroll
        for (int ct = 0; ct < CTH; ++ct) {
            int col = wc * (NC / 2) + 16 * ct + l15;
            float bv = bias ? bias[col] : 0.f;
            float s = 0.f, sq = 0.f;
#pragma unroll
            for (int r = 0; r < 4; ++r) {
                int row = rbase + 16 * rt + quad * 4 + r;
                if (row < NN) {
                    float v = acc[rt][ct][r] + bv;
                    OUT[(size_t)row * NC + col] = f2bf(v);
                    s += v;
                    sq += v * v;
                }
            }
            s += __shfl_xor(s, 16);
            s += __shfl_xor(s, 32);
            sq += __shfl_xor(sq, 16);
            sq += __shfl_xor(sq, 32);
            if (quad == 0) {
                atomicAdd(&csum[col], s);
                atomicAdd(&csq[col], sq);
            }
        }
    }
    __syncthreads();
    for (int i = tid; i < NC; i += 256) {
        unsafeAtomicAdd(&gsum[i], csum[i]);
        unsafeAtomicAdd(&gsq[i], csq[i]);
    }
}

// ---------- BatchNorm params ----------
__global__ void k_bnparam(const float* gsum, const float* gsq, const float* g,
                          const float* be, float* scale, float* shift, int ncols) {
    int c = threadIdx.x;
    if (c < ncols) {
        float m = gsum[c] * (1.f / NN);
        float v = gsq[c] * (1.f / NN) - m * m;
        v = fmaxf(v, 0.f);
        float s = rsqrtf(v + 1e-5f) * g[c];
        scale[c] = s;
        shift[c] = be[c] - m * s;
    }
}

// layers 1,2: write bf16 into XC cols [0,128)
__global__ void k_bnapply_mid(const b16* __restrict__ OUT,
                              const float* __restrict__ scale,
                              const float* __restrict__ shift, b16* __restrict__ XC) {
    int i = blockIdx.x * blockDim.x + threadIdx.x;
    if (i >= NN * 64) return;
    int row = i >> 6, c = (i & 63) * 2;
    ushort2 u = *(const ushort2*)&OUT[(size_t)row * 128 + c];
    float a = fmaf(bf2f(u.x), scale[c], shift[c]);
    float b = fmaf(bf2f(u.y), scale[c + 1], shift[c + 1]);
    a = a > 0.f ? a : 0.01f * a;
    b = b > 0.f ? b : 0.01f * b;
    ushort2 o;
    o.x = f2bf(a);
    o.y = f2bf(b);
    *(ushort2*)&XC[(size_t)row * 512 + c] = o;
}

// layer 3: write d_out (fp32 or bf16 per flag), NC=64
__global__ void k_bnapply_last(const b16* __restrict__ OUT,
                               const float* __restrict__ scale,
                               const float* __restrict__ shift, void* __restrict__ dout,
                               const int* __restrict__ flags) {
    int i = blockIdx.x * blockDim.x + threadIdx.x;
    if (i >= NN * 64) return;
    int c = i & 63;
    float v = fmaf(bf2f(OUT[i]), scale[c], shift[c]);
    v = v > 0.f ? v : 0.01f * v;
    if (flags[0])
        ((float*)dout)[i] = v;
    else
        ((b16*)dout)[i] = f2bf(v);
}

// ---------- driver ----------
#define PB_B1 0
#define PB_B2 128
#define PB_G1 256
#define PB_BE1 384
#define PB_G2 512
#define PB_BE2 640
#define PB_G3 768
#define PB_BE3 832
#define PB_SZ 896

extern "C" void kernel_launch(void* const* d_in, const int* in_sizes, int n_in,
                              void* d_out, int out_size, void* d_ws, size_t ws_size,
                              hipStream_t stream) {
    const void* y   = d_in[0];
    const void* ei  = d_in[1];
    const void* ea  = d_in[2];
    const void* W1  = d_in[3];
    const void* b1  = d_in[4];
    const void* g1  = d_in[5];
    const void* be1 = d_in[6];
    const void* W2  = d_in[7];
    const void* b2  = d_in[8];
    const void* g2  = d_in[9];
    const void* be2 = d_in[10];
    const void* W3  = d_in[11];
    const void* g3  = d_in[12];
    const void* be3 = d_in[13];

    char* w = (char*)d_ws;
    size_t used = 0;
    auto carve = [&](size_t bytes) -> char* {
        char* p = w + used;
        used += (bytes + 255) & ~(size_t)255;
        return p;
    };

    int* flags   = (int*)carve(16);
    int* src32   = (int*)carve((size_t)NE * 4);
    int* dst32   = (int*)carve((size_t)NE * 4);
    float* deg   = (float*)carve((size_t)NN * 4);
    int* cnt     = (int*)carve((size_t)NN * 4);
    int* rowptr  = (int*)carve((size_t)(NN + 1) * 4);
    int* cscan   = (int*)carve((size_t)NN * 4);
    int* bsum    = (int*)carve((size_t)SCAN_NB * 4);
    int* csrc    = (int*)carve((size_t)NE * 4);
    float* cw    = (float*)carve((size_t)NE * 4);
    float* PB    = (float*)carve(PB_SZ * 4);
    b16* Wp1     = (b16*)carve((size_t)512 * 128 * 2);
    b16* Wp2     = (b16*)carve((size_t)512 * 128 * 2);
    b16* Wp3     = (b16*)carve((size_t)512 * 64 * 2);
    b16* OUT     = (b16*)carve((size_t)NN * 128 * 2);
    float* gsum  = (float*)carve(128 * 4);
    float* gsq   = (float*)carve(128 * 4);
    float* scale = (float*)carve(128 * 4);
    float* shift = (float*)carve(128 * 4);
    b16* XC      = (b16*)carve((size_t)NN * 512 * 2);

    // ----- detection + param normalize + weight pack -----
    k_detect<<<1, 64, 0, stream>>>(y, ei, flags);
    auto cvt = [&](const void* in, float* out, int n) {
        k_cvt<<<(n + 127) / 128, 128, 0, stream>>>(in, out, n, flags);
    };
    cvt(b1, PB + PB_B1, 128);
    cvt(b2, PB + PB_B2, 128);
    cvt(g1, PB + PB_G1, 128);
    cvt(be1, PB + PB_BE1, 128);
    cvt(g2, PB + PB_G2, 128);
    cvt(be2, PB + PB_BE2, 128);
    cvt(g3, PB + PB_G3, 64);
    cvt(be3, PB + PB_BE3, 64);
    k_pack<<<(512 * 128 / 8 + 255) / 256, 256, 0, stream>>>(W1, Wp1, 128, flags);
    k_pack<<<(512 * 128 / 8 + 255) / 256, 256, 0, stream>>>(W2, Wp2, 128, flags);
    k_pack<<<(512 * 64 / 8 + 255) / 256, 256, 0, stream>>>(W3, Wp3, 64, flags);

    // ----- graph prep -----
    k_idx<<<(NE + 255) / 256, 256, 0, stream>>>(ei, src32, dst32, flags);
    hipMemsetAsync(deg, 0, (size_t)NN * 4, stream);
    hipMemsetAsync(cnt, 0, (size_t)NN * 4, stream);
    k_degcnt<<<(NE + 255) / 256, 256, 0, stream>>>(dst32, ea, deg, cnt, flags);
    k_dis<<<(NN + 255) / 256, 256, 0, stream>>>(deg);
    k_scan1<<<SCAN_NB, SCAN_B, 0, stream>>>(cnt, cscan, bsum);
    k_scan2<<<1, 64, 0, stream>>>(bsum);
    k_scan3<<<(NN + 255) / 256, 256, 0, stream>>>(cscan, bsum, rowptr);
    hipMemsetAsync(cnt, 0, (size_t)NN * 4, stream);
    k_fill<<<(NE + 255) / 256, 256, 0, stream>>>(src32, dst32, ea, deg, rowptr, cnt,
                                                 csrc, cw, flags);

    // ----- layers -----
    k_cast<<<(NN * 32 + 255) / 256, 256, 0, stream>>>(y, XC, flags);

    auto spmm = [&](int ci, int co) {
        k_spmm<<<(NN * 64 + 255) / 256, 256, 0, stream>>>(XC, ci, co, rowptr, csrc, cw);
    };
    const int gemm_grid = (NN + 63) / 64;

    auto layer = [&](const b16* Wp, const float* bias, const float* g, const float* be,
                     int NC, bool last) {
        spmm(0, 128);
        spmm(128, 256);
        spmm(256, 384);
        hipMemsetAsync(gsum, 0, NC * 4, stream);
        hipMemsetAsync(gsq, 0, NC * 4, stream);
        if (NC == 128)
            k_mgemm<128><<<gemm_grid, 256, 0, stream>>>(XC, Wp, bias, OUT, gsum, gsq);
        else
            k_mgemm<64><<<gemm_grid, 256, 0, stream>>>(XC, Wp, bias, OUT, gsum, gsq);
        k_bnparam<<<1, NC, 0, stream>>>(gsum, gsq, g, be, scale, shift, NC);
        if (last)
            k_bnapply_last<<<(NN * 64 + 255) / 256, 256, 0, stream>>>(OUT, scale, shift,
                                                                      d_out, flags);
        else
            k_bnapply_mid<<<(NN * 64 + 255) / 256, 256, 0, stream>>>(OUT, scale, shift,
                                                                     XC);
    };

    layer(Wp1, PB + PB_B1, PB + PB_G1, PB + PB_BE1, 128, false);
    layer(Wp2, PB + PB_B2, PB + PB_G2, PB + PB_BE2, 128, false);
    layer(Wp3, nullptr, PB + PB_G3, PB + PB_BE3, 64, true);
}

// Round 3
// 799.120 us; speedup vs baseline: 1.0736x; 1.0444x over previous
//
#include <hip/hip_runtime.h>
#include <hip/hip_bf16.h>

typedef unsigned short b16;
typedef __attribute__((ext_vector_type(8))) unsigned short us8;
typedef __attribute__((ext_vector_type(8))) short short8;   // MFMA A/B frag (8 bf16)
typedef __attribute__((ext_vector_type(4))) float float4v;  // MFMA C/D frag

#define NN 100000
#define NE 600000

__device__ __forceinline__ float bf2f(b16 u) {
    return __uint_as_float(((unsigned)u) << 16);
}
__device__ __forceinline__ b16 f2bf(float f) {
    unsigned x = __float_as_uint(f);
    return (b16)((x + 0x7fffu + ((x >> 16) & 1u)) >> 16);
}

// async global->LDS, 16B per lane; LDS dest = wave-uniform base + lane*16
__device__ __forceinline__ void gl2lds16(const b16* g, b16* l) {
    __builtin_amdgcn_global_load_lds(
        (const __attribute__((address_space(1))) void*)g,
        (__attribute__((address_space(3))) void*)l, 16, 0, 0);
}

// ---------- dtype detection: flags[0]=1 if float tensors fp32, flags[1]=1 if idx int64
__global__ void k_detect(const void* __restrict__ y, const void* __restrict__ ei,
                         int* __restrict__ flags) {
    if (threadIdx.x == 0 && blockIdx.x == 0) {
        const b16* p = (const b16*)y;
        int f32 = 0;
        for (int i = 0; i < 128; ++i) {
            float v = bf2f(p[i]);
            if (!(fabsf(v) < 1e4f)) { f32 = 1; break; }
        }
        flags[0] = f32;
        const long long* q = (const long long*)ei;
        int i64 = 1;
        for (int i = 0; i < 4; ++i) {
            long long v = q[i];
            if (v < 0 || v >= NN) i64 = 0;
        }
        flags[1] = i64;
    }
}

__global__ void k_cvt(const void* __restrict__ in, float* __restrict__ out, int n,
                      const int* __restrict__ flags) {
    int i = blockIdx.x * blockDim.x + threadIdx.x;
    if (i >= n) return;
    out[i] = flags[0] ? ((const float*)in)[i] : bf2f(((const b16*)in)[i]);
}

// ---------- edge_index normalize ----------
__global__ void k_idx(const void* __restrict__ ei, int* __restrict__ src32,
                      int* __restrict__ dst32, const int* __restrict__ flags) {
    int e = blockIdx.x * blockDim.x + threadIdx.x;
    if (e >= NE) return;
    int s, d;
    if (flags[1]) {
        const long long* p = (const long long*)ei;
        s = (int)p[e];
        d = (int)p[NE + e];
    } else {
        const int* p = (const int*)ei;
        s = p[e];
        d = p[NE + e];
    }
    src32[e] = ((unsigned)s < NN) ? s : 0;
    dst32[e] = ((unsigned)d < NN) ? d : 0;
}

// ---------- degree (weighted) + CSR count ----------
__global__ void k_degcnt(const int* __restrict__ dst, const void* __restrict__ ea,
                         float* __restrict__ deg, int* __restrict__ cnt,
                         const int* __restrict__ flags) {
    int e = blockIdx.x * blockDim.x + threadIdx.x;
    if (e >= NE) return;
    float w = flags[0] ? ((const float*)ea)[e] : bf2f(((const b16*)ea)[e]);
    int d = dst[e];
    unsafeAtomicAdd(&deg[d], w);
    atomicAdd(&cnt[d], 1);
}

__global__ void k_dis(float* deg) {
    int n = blockIdx.x * blockDim.x + threadIdx.x;
    if (n < NN) {
        float d = deg[n];
        deg[n] = (d > 0.f) ? rsqrtf(fmaxf(d, 1e-12f)) : 0.f;
    }
}

// ---------- 3-phase exclusive scan of cnt[NN] -> rowptr[NN+1] ----------
#define SCAN_B 1024
#define SCAN_NB ((NN + SCAN_B - 1) / SCAN_B)

__global__ __launch_bounds__(SCAN_B) void k_scan1(const int* __restrict__ cnt,
                                                  int* __restrict__ inc,
                                                  int* __restrict__ bsum) {
    __shared__ int s[SCAN_B];
    int i = blockIdx.x * SCAN_B + threadIdx.x;
    s[threadIdx.x] = (i < NN) ? cnt[i] : 0;
    __syncthreads();
    for (int off = 1; off < SCAN_B; off <<= 1) {
        int t = (threadIdx.x >= off) ? s[threadIdx.x - off] : 0;
        __syncthreads();
        s[threadIdx.x] += t;
        __syncthreads();
    }
    if (i < NN) inc[i] = s[threadIdx.x];
    if (threadIdx.x == SCAN_B - 1) bsum[blockIdx.x] = s[SCAN_B - 1];
}

// wave-parallel exclusive scan over SCAN_NB (=98) block sums; 1 wave of 64 lanes
__global__ void k_scan2(int* bsum) {
    int lane = threadIdx.x & 63;
    int a0 = (lane < SCAN_NB) ? bsum[lane] : 0;
    int a1 = (lane + 64 < SCAN_NB) ? bsum[lane + 64] : 0;
#pragma unroll
    for (int off = 1; off < 64; off <<= 1) {
        int t = __shfl_up(a0, off);
        if (lane >= off) a0 += t;
    }
    int tot0 = __shfl(a0, 63);
#pragma unroll
    for (int off = 1; off < 64; off <<= 1) {
        int t = __shfl_up(a1, off);
        if (lane >= off) a1 += t;
    }
    int e0 = __shfl_up(a0, 1);
    if (lane == 0) e0 = 0;
    int e1 = __shfl_up(a1, 1) + tot0;
    if (lane == 0) e1 = tot0;
    if (lane < SCAN_NB) bsum[lane] = e0;
    if (lane + 64 < SCAN_NB) bsum[lane + 64] = e1;
}

__global__ void k_scan3(const int* __restrict__ inc, const int* __restrict__ bsum,
                        int* __restrict__ rowptr) {
    int i = blockIdx.x * blockDim.x + threadIdx.x;
    if (i == 0) rowptr[0] = 0;
    if (i < NN) rowptr[i + 1] = inc[i] + bsum[i / SCAN_B];
}

// ---------- fill CSR ----------
__global__ void k_fill(const int* __restrict__ src, const int* __restrict__ dst,
                       const void* __restrict__ ea, const float* __restrict__ dis,
                       const int* __restrict__ rowptr, int* __restrict__ fill,
                       int* __restrict__ csrc, float* __restrict__ cw,
                       const int* __restrict__ flags) {
    int e = blockIdx.x * blockDim.x + threadIdx.x;
    if (e >= NE) return;
    float a = flags[0] ? ((const float*)ea)[e] : bf2f(((const b16*)ea)[e]);
    int d = dst[e];
    int s = src[e];
    int pos = rowptr[d] + atomicAdd(&fill[d], 1);
    csrc[pos] = s;
    cw[pos] = dis[s] * a * dis[d];
}

// ---------- pack W (fp32/bf16 [512][NC]) into B-fragment order ----------
__global__ void k_pack(const void* __restrict__ W, b16* __restrict__ Wp, int NC,
                       const int* __restrict__ flags) {
    int f = blockIdx.x * blockDim.x + threadIdx.x;
    int total = 512 * NC / 8;
    if (f >= total) return;
    int lane = f & 63;
    int rest = f >> 6;
    int CT = NC >> 4;
    int ct = rest % CT, ks = rest / CT;
    int k0 = 32 * ks + (lane >> 4) * 8;
    int col = 16 * ct + (lane & 15);
    us8 v;
#pragma unroll
    for (int j = 0; j < 8; ++j) {
        float x = flags[0] ? ((const float*)W)[(size_t)(k0 + j) * NC + col]
                           : bf2f(((const b16*)W)[(size_t)(k0 + j) * NC + col]);
        v[j] = f2bf(x);
    }
    *(us8*)&Wp[(size_t)f * 8] = v;
}

// ---------- initial cast y -> XC cols [0,128) (bf16, row stride 512) ----------
__global__ void k_cast(const void* __restrict__ y, b16* __restrict__ XC,
                       const int* __restrict__ flags) {
    int i = blockIdx.x * blockDim.x + threadIdx.x;
    if (i >= NN * 32) return;
    int row = i >> 5, cg = i & 31;
    float4 v;
    if (flags[0]) {
        v = ((const float4*)y)[i];
    } else {
        ushort4 u = ((const ushort4*)y)[i];
        v = make_float4(bf2f(u.x), bf2f(u.y), bf2f(u.z), bf2f(u.w));
    }
    ushort4 o;
    o.x = f2bf(v.x); o.y = f2bf(v.y); o.z = f2bf(v.z); o.w = f2bf(v.w);
    *(ushort4*)&XC[(size_t)row * 512 + 4 * cg] = o;
}

// ---------- SpMM gather: cols [ci,ci+128) -> [co,co+128) ----------
// wave = 1 node; quarter-wave (16 lanes x us8) = 256B row segment per edge.
__global__ __launch_bounds__(256) void k_spmm(b16* __restrict__ XC, int ci, int co,
                                              const int* __restrict__ rowptr,
                                              const int* __restrict__ csrc,
                                              const float* __restrict__ cw) {
    int gid = blockIdx.x * blockDim.x + threadIdx.x;
    int node = gid >> 6;
    if (node >= NN) return;
    int lane = gid & 63;
    int grp = lane >> 4;  // edge slot 0..3
    int l15 = lane & 15;  // 16B chunk within 256B segment
    int beg = rowptr[node], end = rowptr[node + 1];

    float a0[8], a1[8];
#pragma unroll
    for (int j = 0; j < 8; ++j) {
        a0[j] = 0.f;
        a1[j] = 0.f;
    }
    for (int i = beg; i < end; i += 16) {
        int e0 = i + grp, e1 = i + 4 + grp, e2 = i + 8 + grp, e3 = i + 12 + grp;
        float w0 = (e0 < end) ? cw[e0] : 0.f;
        float w1 = (e1 < end) ? cw[e1] : 0.f;
        float w2 = (e2 < end) ? cw[e2] : 0.f;
        float w3 = (e3 < end) ? cw[e3] : 0.f;
        int lim = end - 1;
        int s0 = csrc[e0 < lim ? e0 : lim];
        int s1 = csrc[e1 < lim ? e1 : lim];
        int s2 = csrc[e2 < lim ? e2 : lim];
        int s3 = csrc[e3 < lim ? e3 : lim];
        us8 u0 = *(const us8*)&XC[(size_t)s0 * 512 + ci + 8 * l15];
        us8 u1 = *(const us8*)&XC[(size_t)s1 * 512 + ci + 8 * l15];
        us8 u2 = *(const us8*)&XC[(size_t)s2 * 512 + ci + 8 * l15];
        us8 u3 = *(const us8*)&XC[(size_t)s3 * 512 + ci + 8 * l15];
#pragma unroll
        for (int j = 0; j < 8; ++j) {
            a0[j] = fmaf(w0, bf2f(u0[j]), a0[j]);
            a1[j] = fmaf(w1, bf2f(u1[j]), a1[j]);
            a0[j] = fmaf(w2, bf2f(u2[j]), a0[j]);
            a1[j] = fmaf(w3, bf2f(u3[j]), a1[j]);
        }
    }
#pragma unroll
    for (int j = 0; j < 8; ++j) a0[j] += a1[j];
#pragma unroll
    for (int j = 0; j < 8; ++j) a0[j] += __shfl_xor(a0[j], 16);
#pragma unroll
    for (int j = 0; j < 8; ++j) a0[j] += __shfl_xor(a0[j], 32);
    if (grp == 0) {
        us8 o;
#pragma unroll
        for (int j = 0; j < 8; ++j) o[j] = f2bf(a0[j]);
        *(us8*)&XC[(size_t)node * 512 + co + 8 * l15] = o;
    }
}

// ---------- MFMA GEMM + fused BN-stat epilogue ----------
// OUT[NN x NC](bf16) = XC[NN x 512](bf16) @ Wp (+bias); col sums/sumsq -> gsum/gsq.
// v4 (m97 structure): block = 4 waves = 128 rows x NC cols; K=512 in 8 steps of
// BK=64. Both tiles staged to LDS via async global_load_lds (16B/lane), double
// buffered, ONE __syncthreads per K-step -- loads stay in flight across the
// whole MFMA phase (the compiler cannot defeat this; v1-v3's register prefetch
// was always sunk to its use, leaving MfmaUtil at 5-7%). Tiles are staged in
// MFMA *fragment order* (per-lane global source addresses are free; LDS dest is
// linear lane-order as global_load_lds requires), so every LDS read is a
// contiguous ds_read_b128: bandwidth-limited, no bank conflicts, no swizzle.
// B-tile is a contiguous 16KB slice of packed Wp. Accumulation order identical
// to v0 (ks = 2*kstep+ksub = 0..15). BN-stat arrays overlay the staging LDS
// after the last barrier (keeps static LDS at the 64 KB limit).
template <int NC>
__global__ __launch_bounds__(256) void k_mgemm(const b16* __restrict__ XC,
                                               const b16* __restrict__ Wp,
                                               const float* __restrict__ bias,
                                               b16* __restrict__ OUT,
                                               float* __restrict__ gsum,
                                               float* __restrict__ gsq) {
    constexpr int CT = NC / 16;        // col tiles (8 or 4)
    constexpr int A_ELEM = 8192;       // 16 KB A buffer (128x64 bf16), frag order
    constexpr int B_ELEM = CT * 1024;  // B buffer (64xNC bf16), frag order
    // [A0][A1][B0][B1]; float4v-aligned for ds_read_b128
    __shared__ float4v ldsraw[(2 * A_ELEM + 2 * B_ELEM) / 8];
    b16* lds = (b16*)ldsraw;
    b16* ldsA[2] = {lds, lds + A_ELEM};
    b16* ldsB[2] = {lds + 2 * A_ELEM, lds + 2 * A_ELEM + B_ELEM};

    const int tid = threadIdx.x;
    const int wave = tid >> 6;
    const int lane = tid & 63;
    const int quad = lane >> 4;
    const int l15 = lane & 15;
    const int rbase = blockIdx.x * 128;

    // ---- staging helpers (frag-order chunk id m; LDS byte = m*16) ----
    // A chunk m: rowtile=m>>7 (0..7), ksub=(m>>6)&1, l=m&63 -> r=l&15,q=l>>4
    //   source = XC[(rbase+rowtile*16+r)*512 + kstep*64 + ksub*32 + q*8]
    auto stageA = [&](int kstep, b16* dst) {
#pragma unroll
        for (int c = 0; c < 4; ++c) {
            int m = c * 256 + tid;
            int rowtile = m >> 7;
            int ksub = (m >> 6) & 1;
            int l = m & 63;
            int row = rbase + rowtile * 16 + (l & 15);
            if (row >= NN) row = NN - 1;
            const b16* g = XC + (size_t)row * 512 + kstep * 64 + ksub * 32 +
                           (l >> 4) * 8;
            gl2lds16(g, dst + m * 8);
        }
    };
    // B tile for kstep = contiguous Wp slice [kstep*B_ELEM, (kstep+1)*B_ELEM)
    auto stageB = [&](int kstep, b16* dst) {
        const b16* g0 = Wp + (size_t)kstep * B_ELEM;
#pragma unroll
        for (int c = 0; c < CT / 2; ++c) {
            int m = c * 256 + tid;
            gl2lds16(g0 + m * 8, dst + m * 8);
        }
    };

    float4v acc[2][CT];
#pragma unroll
    for (int rt = 0; rt < 2; ++rt)
#pragma unroll
        for (int ct = 0; ct < CT; ++ct) acc[rt][ct] = (float4v)(0.f);

    stageA(0, ldsA[0]);
    stageB(0, ldsB[0]);
    __syncthreads();  // vmcnt(0) drain + barrier

    int cur = 0;
    for (int t = 0; t < 8; ++t) {
        if (t < 7) {  // issue next-tile async loads; they fly across the MFMAs
            stageA(t + 1, ldsA[cur ^ 1]);
            stageB(t + 1, ldsB[cur ^ 1]);
        }
        const b16* lA = ldsA[cur];
        const b16* lB = ldsB[cur];
#pragma unroll
        for (int ksub = 0; ksub < 2; ++ksub) {
            short8 af[2];
#pragma unroll
            for (int rt = 0; rt < 2; ++rt)
                af[rt] = *(const short8*)(lA +
                                          (((wave * 2 + rt) * 2 + ksub) * 64 + lane) * 8);
#pragma unroll
            for (int ct = 0; ct < CT; ++ct) {
                short8 bf = *(const short8*)(lB + ((ksub * CT + ct) * 64 + lane) * 8);
                acc[0][ct] = __builtin_amdgcn_mfma_f32_16x16x32_bf16(af[0], bf,
                                                                     acc[0][ct], 0, 0, 0);
                acc[1][ct] = __builtin_amdgcn_mfma_f32_16x16x32_bf16(af[1], bf,
                                                                     acc[1][ct], 0, 0, 0);
            }
        }
        __syncthreads();  // drains next-tile vmcnt + all lgkm, then barrier
        cur ^= 1;
    }

    // ---- epilogue: bf16 store + BN stats (C/D: col=lane&15, row=quad*4+reg)
    // staging LDS is dead now (post-barrier); overlay stat arrays on it.
    float* csum = (float*)lds;
    float* csq = csum + NC;
    for (int i = tid; i < 2 * NC; i += 256) csum[i] = 0.f;
    __syncthreads();

    const int wrbase = rbase + wave * 32;
#pragma unroll
    for (int rt = 0; rt < 2; ++rt) {
#pragma unroll
        for (int ct = 0; ct < CT; ++ct) {
            int col = 16 * ct + l15;
            float bv = bias ? bias[col] : 0.f;
            float s = 0.f, sq = 0.f;
#pragma unroll
            for (int r = 0; r < 4; ++r) {
                int row = wrbase + 16 * rt + quad * 4 + r;
                if (row < NN) {
                    float v = acc[rt][ct][r] + bv;
                    OUT[(size_t)row * NC + col] = f2bf(v);
                    s += v;
                    sq += v * v;
                }
            }
            s += __shfl_xor(s, 16);
            s += __shfl_xor(s, 32);
            sq += __shfl_xor(sq, 16);
            sq += __shfl_xor(sq, 32);
            if (quad == 0) {
                atomicAdd(&csum[col], s);
                atomicAdd(&csq[col], sq);
            }
        }
    }
    __syncthreads();
    for (int i = tid; i < NC; i += 256) {
        unsafeAtomicAdd(&gsum[i], csum[i]);
        unsafeAtomicAdd(&gsq[i], csq[i]);
    }
}

// ---------- BatchNorm params ----------
__global__ void k_bnparam(const float* gsum, const float* gsq, const float* g,
                          const float* be, float* scale, float* shift, int ncols) {
    int c = threadIdx.x;
    if (c < ncols) {
        float m = gsum[c] * (1.f / NN);
        float v = gsq[c] * (1.f / NN) - m * m;
        v = fmaxf(v, 0.f);
        float s = rsqrtf(v + 1e-5f) * g[c];
        scale[c] = s;
        shift[c] = be[c] - m * s;
    }
}

// layers 1,2: write bf16 into XC cols [0,128)
__global__ void k_bnapply_mid(const b16* __restrict__ OUT,
                              const float* __restrict__ scale,
                              const float* __restrict__ shift, b16* __restrict__ XC) {
    int i = blockIdx.x * blockDim.x + threadIdx.x;
    if (i >= NN * 64) return;
    int row = i >> 6, c = (i & 63) * 2;
    ushort2 u = *(const ushort2*)&OUT[(size_t)row * 128 + c];
    float a = fmaf(bf2f(u.x), scale[c], shift[c]);
    float b = fmaf(bf2f(u.y), scale[c + 1], shift[c + 1]);
    a = a > 0.f ? a : 0.01f * a;
    b = b > 0.f ? b : 0.01f * b;
    ushort2 o;
    o.x = f2bf(a);
    o.y = f2bf(b);
    *(ushort2*)&XC[(size_t)row * 512 + c] = o;
}

// layer 3: write d_out (fp32 or bf16 per flag), NC=64
__global__ void k_bnapply_last(const b16* __restrict__ OUT,
                               const float* __restrict__ scale,
                               const float* __restrict__ shift, void* __restrict__ dout,
                               const int* __restrict__ flags) {
    int i = blockIdx.x * blockDim.x + threadIdx.x;
    if (i >= NN * 64) return;
    int c = i & 63;
    float v = fmaf(bf2f(OUT[i]), scale[c], shift[c]);
    v = v > 0.f ? v : 0.01f * v;
    if (flags[0])
        ((float*)dout)[i] = v;
    else
        ((b16*)dout)[i] = f2bf(v);
}

// ---------- driver ----------
#define PB_B1 0
#define PB_B2 128
#define PB_G1 256
#define PB_BE1 384
#define PB_G2 512
#define PB_BE2 640
#define PB_G3 768
#define PB_BE3 832
#define PB_SZ 896

extern "C" void kernel_launch(void* const* d_in, const int* in_sizes, int n_in,
                              void* d_out, int out_size, void* d_ws, size_t ws_size,
                              hipStream_t stream) {
    const void* y   = d_in[0];
    const void* ei  = d_in[1];
    const void* ea  = d_in[2];
    const void* W1  = d_in[3];
    const void* b1  = d_in[4];
    const void* g1  = d_in[5];
    const void* be1 = d_in[6];
    const void* W2  = d_in[7];
    const void* b2  = d_in[8];
    const void* g2  = d_in[9];
    const void* be2 = d_in[10];
    const void* W3  = d_in[11];
    const void* g3  = d_in[12];
    const void* be3 = d_in[13];

    char* w = (char*)d_ws;
    size_t used = 0;
    auto carve = [&](size_t bytes) -> char* {
        char* p = w + used;
        used += (bytes + 255) & ~(size_t)255;
        return p;
    };

    int* flags   = (int*)carve(16);
    int* src32   = (int*)carve((size_t)NE * 4);
    int* dst32   = (int*)carve((size_t)NE * 4);
    float* deg   = (float*)carve((size_t)NN * 4);
    int* cnt     = (int*)carve((size_t)NN * 4);
    int* rowptr  = (int*)carve((size_t)(NN + 1) * 4);
    int* cscan   = (int*)carve((size_t)NN * 4);
    int* bsum    = (int*)carve((size_t)SCAN_NB * 4);
    int* csrc    = (int*)carve((size_t)NE * 4);
    float* cw    = (float*)carve((size_t)NE * 4);
    float* PB    = (float*)carve(PB_SZ * 4);
    b16* Wp1     = (b16*)carve((size_t)512 * 128 * 2);
    b16* Wp2     = (b16*)carve((size_t)512 * 128 * 2);
    b16* Wp3     = (b16*)carve((size_t)512 * 64 * 2);
    b16* OUT     = (b16*)carve((size_t)NN * 128 * 2);
    float* gsum  = (float*)carve(128 * 4);
    float* gsq   = (float*)carve(128 * 4);
    float* scale = (float*)carve(128 * 4);
    float* shift = (float*)carve(128 * 4);
    b16* XC      = (b16*)carve((size_t)NN * 512 * 2);

    // ----- detection + param normalize + weight pack -----
    k_detect<<<1, 64, 0, stream>>>(y, ei, flags);
    auto cvt = [&](const void* in, float* out, int n) {
        k_cvt<<<(n + 127) / 128, 128, 0, stream>>>(in, out, n, flags);
    };
    cvt(b1, PB + PB_B1, 128);
    cvt(b2, PB + PB_B2, 128);
    cvt(g1, PB + PB_G1, 128);
    cvt(be1, PB + PB_BE1, 128);
    cvt(g2, PB + PB_G2, 128);
    cvt(be2, PB + PB_BE2, 128);
    cvt(g3, PB + PB_G3, 64);
    cvt(be3, PB + PB_BE3, 64);
    k_pack<<<(512 * 128 / 8 + 255) / 256, 256, 0, stream>>>(W1, Wp1, 128, flags);
    k_pack<<<(512 * 128 / 8 + 255) / 256, 256, 0, stream>>>(W2, Wp2, 128, flags);
    k_pack<<<(512 * 64 / 8 + 255) / 256, 256, 0, stream>>>(W3, Wp3, 64, flags);

    // ----- graph prep -----
    k_idx<<<(NE + 255) / 256, 256, 0, stream>>>(ei, src32, dst32, flags);
    hipMemsetAsync(deg, 0, (size_t)NN * 4, stream);
    hipMemsetAsync(cnt, 0, (size_t)NN * 4, stream);
    k_degcnt<<<(NE + 255) / 256, 256, 0, stream>>>(dst32, ea, deg, cnt, flags);
    k_dis<<<(NN + 255) / 256, 256, 0, stream>>>(deg);
    k_scan1<<<SCAN_NB, SCAN_B, 0, stream>>>(cnt, cscan, bsum);
    k_scan2<<<1, 64, 0, stream>>>(bsum);
    k_scan3<<<(NN + 255) / 256, 256, 0, stream>>>(cscan, bsum, rowptr);
    hipMemsetAsync(cnt, 0, (size_t)NN * 4, stream);
    k_fill<<<(NE + 255) / 256, 256, 0, stream>>>(src32, dst32, ea, deg, rowptr, cnt,
                                                 csrc, cw, flags);

    // ----- layers -----
    k_cast<<<(NN * 32 + 255) / 256, 256, 0, stream>>>(y, XC, flags);

    auto spmm = [&](int ci, int co) {
        k_spmm<<<(NN * 64 + 255) / 256, 256, 0, stream>>>(XC, ci, co, rowptr, csrc, cw);
    };
    const int gemm_grid = (NN + 127) / 128;

    auto layer = [&](const b16* Wp, const float* bias, const float* g, const float* be,
                     int NC, bool last) {
        spmm(0, 128);
        spmm(128, 256);
        spmm(256, 384);
        hipMemsetAsync(gsum, 0, NC * 4, stream);
        hipMemsetAsync(gsq, 0, NC * 4, stream);
        if (NC == 128)
            k_mgemm<128><<<gemm_grid, 256, 0, stream>>>(XC, Wp, bias, OUT, gsum, gsq);
        else
            k_mgemm<64><<<gemm_grid, 256, 0, stream>>>(XC, Wp, bias, OUT, gsum, gsq);
        k_bnparam<<<1, NC, 0, stream>>>(gsum, gsq, g, be, scale, shift, NC);
        if (last)
            k_bnapply_last<<<(NN * 64 + 255) / 256, 256, 0, stream>>>(OUT, scale, shift,
                                                                      d_out, flags);
        else
            k_bnapply_mid<<<(NN * 64 + 255) / 256, 256, 0, stream>>>(OUT, scale, shift,
                                                                     XC);
    };

    layer(Wp1, PB + PB_B1, PB + PB_G1, PB + PB_BE1, 128, false);
    layer(Wp2, PB + PB_B2, PB + PB_G2, PB + PB_BE2, 128, false);
    layer(Wp3, nullptr, PB + PB_G3, PB + PB_BE3, 64, true);
}

// Round 5
// 755.940 us; speedup vs baseline: 1.1349x; 1.0571x over previous
//
#include <hip/hip_runtime.h>
#include <hip/hip_bf16.h>

typedef unsigned short b16;
typedef __attribute__((ext_vector_type(8))) unsigned short us8;
typedef __attribute__((ext_vector_type(8))) short short8;   // MFMA A/B frag (8 bf16)
typedef __attribute__((ext_vector_type(4))) float float4v;  // MFMA C/D frag

#define NN 100000
#define NE 600000

__device__ __forceinline__ float bf2f(b16 u) {
    return __uint_as_float(((unsigned)u) << 16);
}
__device__ __forceinline__ b16 f2bf(float f) {
    unsigned x = __float_as_uint(f);
    return (b16)((x + 0x7fffu + ((x >> 16) & 1u)) >> 16);
}

// ---------- dtype detection: flags[0]=1 if float tensors fp32, flags[1]=1 if idx int64
__global__ void k_detect(const void* __restrict__ y, const void* __restrict__ ei,
                         int* __restrict__ flags) {
    if (threadIdx.x == 0 && blockIdx.x == 0) {
        const b16* p = (const b16*)y;
        int f32 = 0;
        for (int i = 0; i < 128; ++i) {
            float v = bf2f(p[i]);
            if (!(fabsf(v) < 1e4f)) { f32 = 1; break; }
        }
        flags[0] = f32;
        const long long* q = (const long long*)ei;
        int i64 = 1;
        for (int i = 0; i < 4; ++i) {
            long long v = q[i];
            if (v < 0 || v >= NN) i64 = 0;
        }
        flags[1] = i64;
    }
}

// ---------- all 8 small param vectors -> PB (fp32) in one launch ----------
#define PB_B1 0
#define PB_B2 128
#define PB_G1 256
#define PB_BE1 384
#define PB_G2 512
#define PB_BE2 640
#define PB_G3 768
#define PB_BE3 832
#define PB_SZ 896

__global__ void k_cvtall(const void* b1, const void* b2, const void* g1,
                         const void* be1, const void* g2, const void* be2,
                         const void* g3, const void* be3, float* __restrict__ PB,
                         const int* __restrict__ flags) {
    int i = blockIdx.x * blockDim.x + threadIdx.x;
    if (i >= PB_SZ) return;
    const void* srcs[8] = {b1, b2, g1, be1, g2, be2, g3, be3};
    int seg, off;
    if (i < 768) { seg = i >> 7; off = seg << 7; }
    else if (i < 832) { seg = 6; off = 768; }
    else { seg = 7; off = 832; }
    int idx = i - off;
    const void* s = srcs[seg];
    PB[i] = flags[0] ? ((const float*)s)[idx] : bf2f(((const b16*)s)[idx]);
}

// ---------- edge_index normalize (+ zero deg/cnt for later kernels) ----------
__global__ void k_idx(const void* __restrict__ ei, int* __restrict__ src32,
                      int* __restrict__ dst32, const int* __restrict__ flags,
                      float* __restrict__ deg, int* __restrict__ cnt) {
    int e = blockIdx.x * blockDim.x + threadIdx.x;
    if (e < NN) { deg[e] = 0.f; cnt[e] = 0; }
    if (e >= NE) return;
    int s, d;
    if (flags[1]) {
        const long long* p = (const long long*)ei;
        s = (int)p[e];
        d = (int)p[NE + e];
    } else {
        const int* p = (const int*)ei;
        s = p[e];
        d = p[NE + e];
    }
    src32[e] = ((unsigned)s < NN) ? s : 0;
    dst32[e] = ((unsigned)d < NN) ? d : 0;
}

// ---------- degree (weighted) + CSR count ----------
__global__ void k_degcnt(const int* __restrict__ dst, const void* __restrict__ ea,
                         float* __restrict__ deg, int* __restrict__ cnt,
                         const int* __restrict__ flags) {
    int e = blockIdx.x * blockDim.x + threadIdx.x;
    if (e >= NE) return;
    float w = flags[0] ? ((const float*)ea)[e] : bf2f(((const b16*)ea)[e]);
    int d = dst[e];
    unsafeAtomicAdd(&deg[d], w);
    atomicAdd(&cnt[d], 1);
}

// ---------- 3-phase exclusive scan of cnt[NN] -> rowptr[NN+1] ----------
#define SCAN_B 1024
#define SCAN_NB ((NN + SCAN_B - 1) / SCAN_B)

// also performs the deg -> rsqrt(deg) transform (was k_dis)
__global__ __launch_bounds__(SCAN_B) void k_scan1(const int* __restrict__ cnt,
                                                  int* __restrict__ inc,
                                                  int* __restrict__ bsum,
                                                  float* __restrict__ deg) {
    __shared__ int s[SCAN_B];
    int i = blockIdx.x * SCAN_B + threadIdx.x;
    if (i < NN) {
        float d = deg[i];
        deg[i] = (d > 0.f) ? rsqrtf(fmaxf(d, 1e-12f)) : 0.f;
    }
    s[threadIdx.x] = (i < NN) ? cnt[i] : 0;
    __syncthreads();
    for (int off = 1; off < SCAN_B; off <<= 1) {
        int t = (threadIdx.x >= off) ? s[threadIdx.x - off] : 0;
        __syncthreads();
        s[threadIdx.x] += t;
        __syncthreads();
    }
    if (i < NN) inc[i] = s[threadIdx.x];
    if (threadIdx.x == SCAN_B - 1) bsum[blockIdx.x] = s[SCAN_B - 1];
}

// wave-parallel exclusive scan over SCAN_NB (=98) block sums; 1 wave of 64 lanes
__global__ void k_scan2(int* bsum) {
    int lane = threadIdx.x & 63;
    int a0 = (lane < SCAN_NB) ? bsum[lane] : 0;
    int a1 = (lane + 64 < SCAN_NB) ? bsum[lane + 64] : 0;
#pragma unroll
    for (int off = 1; off < 64; off <<= 1) {
        int t = __shfl_up(a0, off);
        if (lane >= off) a0 += t;
    }
    int tot0 = __shfl(a0, 63);
#pragma unroll
    for (int off = 1; off < 64; off <<= 1) {
        int t = __shfl_up(a1, off);
        if (lane >= off) a1 += t;
    }
    int e0 = __shfl_up(a0, 1);
    if (lane == 0) e0 = 0;
    int e1 = __shfl_up(a1, 1) + tot0;
    if (lane == 0) e1 = tot0;
    if (lane < SCAN_NB) bsum[lane] = e0;
    if (lane + 64 < SCAN_NB) bsum[lane + 64] = e1;
}

// also re-zeroes cnt (used as fill cursor by k_fill)
__global__ void k_scan3(const int* __restrict__ inc, const int* __restrict__ bsum,
                        int* __restrict__ rowptr, int* __restrict__ cnt) {
    int i = blockIdx.x * blockDim.x + threadIdx.x;
    if (i == 0) rowptr[0] = 0;
    if (i < NN) {
        rowptr[i + 1] = inc[i] + bsum[i / SCAN_B];
        cnt[i] = 0;
    }
}

// ---------- fill CSR ----------
__global__ void k_fill(const int* __restrict__ src, const int* __restrict__ dst,
                       const void* __restrict__ ea, const float* __restrict__ dis,
                       const int* __restrict__ rowptr, int* __restrict__ fill,
                       int* __restrict__ csrc, float* __restrict__ cw,
                       const int* __restrict__ flags) {
    int e = blockIdx.x * blockDim.x + threadIdx.x;
    if (e >= NE) return;
    float a = flags[0] ? ((const float*)ea)[e] : bf2f(((const b16*)ea)[e]);
    int d = dst[e];
    int s = src[e];
    int pos = rowptr[d] + atomicAdd(&fill[d], 1);
    csrc[pos] = s;
    cw[pos] = dis[s] * a * dis[d];
}

// ---------- pack W (fp32/bf16 [512][NC]) into B-fragment order ----------
__global__ void k_pack(const void* __restrict__ W, b16* __restrict__ Wp, int NC,
                       const int* __restrict__ flags) {
    int f = blockIdx.x * blockDim.x + threadIdx.x;
    int total = 512 * NC / 8;
    if (f >= total) return;
    int lane = f & 63;
    int rest = f >> 6;
    int CT = NC >> 4;
    int ct = rest % CT, ks = rest / CT;
    int k0 = 32 * ks + (lane >> 4) * 8;
    int col = 16 * ct + (lane & 15);
    us8 v;
#pragma unroll
    for (int j = 0; j < 8; ++j) {
        float x = flags[0] ? ((const float*)W)[(size_t)(k0 + j) * NC + col]
                           : bf2f(((const b16*)W)[(size_t)(k0 + j) * NC + col]);
        v[j] = f2bf(x);
    }
    *(us8*)&Wp[(size_t)f * 8] = v;
}

// ---------- initial cast y -> XC cols [0,128); also zero per-layer BN stats ----
__global__ void k_cast(const void* __restrict__ y, b16* __restrict__ XC,
                       const int* __restrict__ flags, float* __restrict__ gstat) {
    int i = blockIdx.x * blockDim.x + threadIdx.x;
    if (i < 768) gstat[i] = 0.f;  // 3 layers x (128 sum + 128 sq)
    if (i >= NN * 32) return;
    int row = i >> 5, cg = i & 31;
    float4 v;
    if (flags[0]) {
        v = ((const float4*)y)[i];
    } else {
        ushort4 u = ((const ushort4*)y)[i];
        v = make_float4(bf2f(u.x), bf2f(u.y), bf2f(u.z), bf2f(u.w));
    }
    ushort4 o;
    o.x = f2bf(v.x); o.y = f2bf(v.y); o.z = f2bf(v.z); o.w = f2bf(v.w);
    *(ushort4*)&XC[(size_t)row * 512 + 4 * cg] = o;
}

// ---------- SpMM gather: cols [ci,ci+128) -> [co,co+128) ----------
// wave = 1 node; quarter-wave (16 lanes x us8) = 256B row segment per edge.
// v5: 8-edge chunks (2 slots x 4 groups). Mean degree = 6 (Poisson), so 84% of
// nodes finish in ONE chunk issuing 2 gathers/lane instead of 4 (the 16-chunk
// version issued 2.7x more gathers than edges; clamped dups hit L1 but still
// burn VMEM issue slots and latency). deg 9..16 nodes issue the same 4 as before.
__global__ __launch_bounds__(256) void k_spmm(b16* __restrict__ XC, int ci, int co,
                                              const int* __restrict__ rowptr,
                                              const int* __restrict__ csrc,
                                              const float* __restrict__ cw) {
    int gid = blockIdx.x * blockDim.x + threadIdx.x;
    int node = gid >> 6;
    if (node >= NN) return;
    int lane = gid & 63;
    int grp = lane >> 4;  // edge slot group 0..3
    int l15 = lane & 15;  // 16B chunk within 256B segment
    int beg = rowptr[node], end = rowptr[node + 1];

    float a0[8], a1[8];
#pragma unroll
    for (int j = 0; j < 8; ++j) {
        a0[j] = 0.f;
        a1[j] = 0.f;
    }
    for (int i = beg; i < end; i += 8) {
        int e0 = i + grp, e1 = i + 4 + grp;
        float w0 = (e0 < end) ? cw[e0] : 0.f;
        float w1 = (e1 < end) ? cw[e1] : 0.f;
        int lim = end - 1;
        int s0 = csrc[e0 < lim ? e0 : lim];
        int s1 = csrc[e1 < lim ? e1 : lim];
        us8 u0 = *(const us8*)&XC[(size_t)s0 * 512 + ci + 8 * l15];
        us8 u1 = *(const us8*)&XC[(size_t)s1 * 512 + ci + 8 * l15];
#pragma unroll
        for (int j = 0; j < 8; ++j) {
            a0[j] = fmaf(w0, bf2f(u0[j]), a0[j]);
            a1[j] = fmaf(w1, bf2f(u1[j]), a1[j]);
        }
    }
#pragma unroll
    for (int j = 0; j < 8; ++j) a0[j] += a1[j];
#pragma unroll
    for (int j = 0; j < 8; ++j) a0[j] += __shfl_xor(a0[j], 16);
#pragma unroll
    for (int j = 0; j < 8; ++j) a0[j] += __shfl_xor(a0[j], 32);
    if (grp == 0) {
        us8 o;
#pragma unroll
        for (int j = 0; j < 8; ++j) o[j] = f2bf(a0[j]);
        *(us8*)&XC[(size_t)node * 512 + co + 8 * l15] = o;
    }
}

// ---------- MFMA GEMM + fused BN-stat epilogue (round-0 v0, best measured) ----
// OUT[NN x NC](bf16) = XC[NN x 512](bf16) @ Wp (+bias); col sums/sumsq -> gsum/gsq.
// NO LDS staging, NO barriers in main loop: A frags (16B contiguous) and packed-B
// frags loaded straight from global into registers, depth-1 prefetch. Wave owns
// 32 rows (2 row-tiles of 16) x all NC cols; block = 4 waves = 128 rows.
template <int NC>
__global__ __launch_bounds__(256) void k_mgemm(const b16* __restrict__ XC,
                                               const b16* __restrict__ Wp,
                                               const float* __restrict__ bias,
                                               b16* __restrict__ OUT,
                                               float* __restrict__ gsum,
                                               float* __restrict__ gsq) {
    constexpr int CT = NC / 16;
    __shared__ float csum[NC], csq[NC];
    const int tid = threadIdx.x;
    const int wave = tid >> 6;
    const int lane = tid & 63;
    const int quad = lane >> 4;
    const int l15 = lane & 15;
    const int rbase = blockIdx.x * 128 + wave * 32;

    for (int i = tid; i < NC; i += 256) {
        csum[i] = 0.f;
        csq[i] = 0.f;
    }

    float4v acc[2][CT];
#pragma unroll
    for (int rt = 0; rt < 2; ++rt)
#pragma unroll
        for (int ct = 0; ct < CT; ++ct) acc[rt][ct] = (float4v)(0.f);

    const b16* gA[2];
#pragma unroll
    for (int rt = 0; rt < 2; ++rt) {
        int r = rbase + 16 * rt + l15;
        if (r >= NN) r = NN - 1;  // clamp; dead rows excluded from store/stats
        gA[rt] = XC + (size_t)r * 512 + quad * 8;
    }
    const b16* gB = Wp + lane * 8;

    short8 afc[2], bfc[CT], afn[2], bfn[CT];
#pragma unroll
    for (int rt = 0; rt < 2; ++rt) afc[rt] = *(const short8*)(gA[rt]);
#pragma unroll
    for (int ct = 0; ct < CT; ++ct) bfc[ct] = *(const short8*)(gB + ct * 512);

    for (int ks = 0; ks < 16; ++ks) {
        if (ks < 15) {  // prefetch next k-step into regs (issues before MFMA waits)
#pragma unroll
            for (int rt = 0; rt < 2; ++rt)
                afn[rt] = *(const short8*)(gA[rt] + 32 * (ks + 1));
#pragma unroll
            for (int ct = 0; ct < CT; ++ct)
                bfn[ct] = *(const short8*)(gB + (size_t)((ks + 1) * CT + ct) * 512);
        }
#pragma unroll
        for (int rt = 0; rt < 2; ++rt)
#pragma unroll
            for (int ct = 0; ct < CT; ++ct)
                acc[rt][ct] = __builtin_amdgcn_mfma_f32_16x16x32_bf16(
                    afc[rt], bfc[ct], acc[rt][ct], 0, 0, 0);
        if (ks < 15) {
#pragma unroll
            for (int rt = 0; rt < 2; ++rt) afc[rt] = afn[rt];
#pragma unroll
            for (int ct = 0; ct < CT; ++ct) bfc[ct] = bfn[ct];
        }
    }

    // epilogue: bf16 store + BN stats (C/D: col=lane&15, row=quad*4+reg)
#pragma unroll
    for (int rt = 0; rt < 2; ++rt) {
#pragma unroll
        for (int ct = 0; ct < CT; ++ct) {
            int col = 16 * ct + l15;
            float bv = bias ? bias[col] : 0.f;
            float s = 0.f, sq = 0.f;
#pragma unroll
            for (int r = 0; r < 4; ++r) {
                int row = rbase + 16 * rt + quad * 4 + r;
                if (row < NN) {
                    float v = acc[rt][ct][r] + bv;
                    OUT[(size_t)row * NC + col] = f2bf(v);
                    s += v;
                    sq += v * v;
                }
            }
            s += __shfl_xor(s, 16);
            s += __shfl_xor(s, 32);
            sq += __shfl_xor(sq, 16);
            sq += __shfl_xor(sq, 32);
            if (quad == 0) {
                atomicAdd(&csum[col], s);
                atomicAdd(&csq[col], sq);
            }
        }
    }
    __syncthreads();
    for (int i = tid; i < NC; i += 256) {
        unsafeAtomicAdd(&gsum[i], csum[i]);
        unsafeAtomicAdd(&gsq[i], csq[i]);
    }
}

// ---------- BatchNorm params ----------
__global__ void k_bnparam(const float* gsum, const float* gsq, const float* g,
                          const float* be, float* scale, float* shift, int ncols) {
    int c = threadIdx.x;
    if (c < ncols) {
        float m = gsum[c] * (1.f / NN);
        float v = gsq[c] * (1.f / NN) - m * m;
        v = fmaxf(v, 0.f);
        float s = rsqrtf(v + 1e-5f) * g[c];
        scale[c] = s;
        shift[c] = be[c] - m * s;
    }
}

// layers 1,2: write bf16 into XC cols [0,128)
__global__ void k_bnapply_mid(const b16* __restrict__ OUT,
                              const float* __restrict__ scale,
                              const float* __restrict__ shift, b16* __restrict__ XC) {
    int i = blockIdx.x * blockDim.x + threadIdx.x;
    if (i >= NN * 64) return;
    int row = i >> 6, c = (i & 63) * 2;
    ushort2 u = *(const ushort2*)&OUT[(size_t)row * 128 + c];
    float a = fmaf(bf2f(u.x), scale[c], shift[c]);
    float b = fmaf(bf2f(u.y), scale[c + 1], shift[c + 1]);
    a = a > 0.f ? a : 0.01f * a;
    b = b > 0.f ? b : 0.01f * b;
    ushort2 o;
    o.x = f2bf(a);
    o.y = f2bf(b);
    *(ushort2*)&XC[(size_t)row * 512 + c] = o;
}

// layer 3: write d_out (fp32 or bf16 per flag), NC=64
__global__ void k_bnapply_last(const b16* __restrict__ OUT,
                               const float* __restrict__ scale,
                               const float* __restrict__ shift, void* __restrict__ dout,
                               const int* __restrict__ flags) {
    int i = blockIdx.x * blockDim.x + threadIdx.x;
    if (i >= NN * 64) return;
    int c = i & 63;
    float v = fmaf(bf2f(OUT[i]), scale[c], shift[c]);
    v = v > 0.f ? v : 0.01f * v;
    if (flags[0])
        ((float*)dout)[i] = v;
    else
        ((b16*)dout)[i] = f2bf(v);
}

// ---------- driver ----------
extern "C" void kernel_launch(void* const* d_in, const int* in_sizes, int n_in,
                              void* d_out, int out_size, void* d_ws, size_t ws_size,
                              hipStream_t stream) {
    const void* y   = d_in[0];
    const void* ei  = d_in[1];
    const void* ea  = d_in[2];
    const void* W1  = d_in[3];
    const void* b1  = d_in[4];
    const void* g1  = d_in[5];
    const void* be1 = d_in[6];
    const void* W2  = d_in[7];
    const void* b2  = d_in[8];
    const void* g2  = d_in[9];
    const void* be2 = d_in[10];
    const void* W3  = d_in[11];
    const void* g3  = d_in[12];
    const void* be3 = d_in[13];

    char* w = (char*)d_ws;
    size_t used = 0;
    auto carve = [&](size_t bytes) -> char* {
        char* p = w + used;
        used += (bytes + 255) & ~(size_t)255;
        return p;
    };

    int* flags   = (int*)carve(16);
    int* src32   = (int*)carve((size_t)NE * 4);
    int* dst32   = (int*)carve((size_t)NE * 4);
    float* deg   = (float*)carve((size_t)NN * 4);
    int* cnt     = (int*)carve((size_t)NN * 4);
    int* rowptr  = (int*)carve((size_t)(NN + 1) * 4);
    int* cscan   = (int*)carve((size_t)NN * 4);
    int* bsum    = (int*)carve((size_t)SCAN_NB * 4);
    int* csrc    = (int*)carve((size_t)NE * 4);
    float* cw    = (float*)carve((size_t)NE * 4);
    float* PB    = (float*)carve(PB_SZ * 4);
    b16* Wp1     = (b16*)carve((size_t)512 * 128 * 2);
    b16* Wp2     = (b16*)carve((size_t)512 * 128 * 2);
    b16* Wp3     = (b16*)carve((size_t)512 * 64 * 2);
    b16* OUT     = (b16*)carve((size_t)NN * 128 * 2);
    float* gstat = (float*)carve(768 * 4);  // 3 layers x (128 sum + 128 sq)
    float* scale = (float*)carve(128 * 4);
    float* shift = (float*)carve(128 * 4);
    b16* XC      = (b16*)carve((size_t)NN * 512 * 2);

    // ----- detection + param normalize + weight pack -----
    k_detect<<<1, 64, 0, stream>>>(y, ei, flags);
    k_cvtall<<<(PB_SZ + 255) / 256, 256, 0, stream>>>(b1, b2, g1, be1, g2, be2, g3,
                                                      be3, PB, flags);
    k_pack<<<(512 * 128 / 8 + 255) / 256, 256, 0, stream>>>(W1, Wp1, 128, flags);
    k_pack<<<(512 * 128 / 8 + 255) / 256, 256, 0, stream>>>(W2, Wp2, 128, flags);
    k_pack<<<(512 * 64 / 8 + 255) / 256, 256, 0, stream>>>(W3, Wp3, 64, flags);

    // ----- graph prep (deg/cnt zeroed inside k_idx; dis fused into k_scan1;
    //        cnt re-zero fused into k_scan3) -----
    k_idx<<<(NE + 255) / 256, 256, 0, stream>>>(ei, src32, dst32, flags, deg, cnt);
    k_degcnt<<<(NE + 255) / 256, 256, 0, stream>>>(dst32, ea, deg, cnt, flags);
    k_scan1<<<SCAN_NB, SCAN_B, 0, stream>>>(cnt, cscan, bsum, deg);
    k_scan2<<<1, 64, 0, stream>>>(bsum);
    k_scan3<<<(NN + 255) / 256, 256, 0, stream>>>(cscan, bsum, rowptr, cnt);
    k_fill<<<(NE + 255) / 256, 256, 0, stream>>>(src32, dst32, ea, deg, rowptr, cnt,
                                                 csrc, cw, flags);

    // ----- layers -----
    k_cast<<<(NN * 32 + 255) / 256, 256, 0, stream>>>(y, XC, flags, gstat);

    auto spmm = [&](int ci, int co) {
        k_spmm<<<(NN * 64 + 255) / 256, 256, 0, stream>>>(XC, ci, co, rowptr, csrc, cw);
    };
    const int gemm_grid = (NN + 127) / 128;

    auto layer = [&](int li, const b16* Wp, const float* bias, const float* g,
                     const float* be, int NC, bool last) {
        spmm(0, 128);
        spmm(128, 256);
        spmm(256, 384);
        float* gs = gstat + li * 256;
        float* gq = gs + 128;
        if (NC == 128)
            k_mgemm<128><<<gemm_grid, 256, 0, stream>>>(XC, Wp, bias, OUT, gs, gq);
        else
            k_mgemm<64><<<gemm_grid, 256, 0, stream>>>(XC, Wp, bias, OUT, gs, gq);
        k_bnparam<<<1, NC, 0, stream>>>(gs, gq, g, be, scale, shift, NC);
        if (last)
            k_bnapply_last<<<(NN * 64 + 255) / 256, 256, 0, stream>>>(OUT, scale, shift,
                                                                      d_out, flags);
        else
            k_bnapply_mid<<<(NN * 64 + 255) / 256, 256, 0, stream>>>(OUT, scale, shift,
                                                                     XC);
    };

    layer(0, Wp1, PB + PB_B1, PB + PB_G1, PB + PB_BE1, 128, false);
    layer(1, Wp2, PB + PB_B2, PB + PB_G2, PB + PB_BE2, 128, false);
    layer(2, Wp3, nullptr, PB + PB_G3, PB + PB_BE3, 64, true);
}